// Round 5
// baseline (1916.321 us; speedup 1.0000x reference)
//
#include <hip/hip_runtime.h>
#include <hip/hip_fp16.h>

#define FDIM 64
#define PCAP 400000   // per-partition capacity (expected ~170K max, 2.4x headroom)

// ---- detect whether edge_index is int64 (high dwords all zero) or int32 ----
__global__ void detect_dtype_kernel(const int* ei, int nsamp, int* flag) {
    __shared__ int any_nz;
    if (threadIdx.x == 0) any_nz = 0;
    __syncthreads();
    int local = 0;
    for (int i = threadIdx.x; i < nsamp; i += blockDim.x) {
        if (ei[2 * i + 1] != 0) local = 1;   // odd dword: int64 high word (==0) vs real int32 index
    }
    if (local) atomicOr(&any_nz, 1);
    __syncthreads();
    if (threadIdx.x == 0) flag[0] = (any_nz == 0) ? 1 : 0;   // 1 => int64
}

// ---- single pass: convert, count deg, partition (src,dst) into 8 XCD-group streams ----
__global__ __launch_bounds__(256) void convert_partition(const void* ei, const int* flag, int E,
                                                         int* __restrict__ deg,
                                                         int* __restrict__ pcount,
                                                         int2* __restrict__ parts) {
    int is64 = flag[0];
    int lane = threadIdx.x & 63;
    int gtid = blockIdx.x * blockDim.x + threadIdx.x;
    int stride = gridDim.x * blockDim.x;
    for (int base = gtid - lane; base < E; base += stride) {   // wave-uniform base
        int i = base + lane;
        bool valid = i < E;
        int s = 0, d = 0;
        if (valid) {
            if (is64) {
                const long long* p = (const long long*)ei;
                s = (int)p[i]; d = (int)p[E + i];
            } else {
                const int* p = (const int*)ei;
                s = p[i]; d = p[E + i];
            }
            atomicAdd(&deg[d], 1);
        }
        int p = valid ? ((d >> 12) & 7) : -1;
        #pragma unroll
        for (int pp = 0; pp < 8; pp++) {
            unsigned long long m = __ballot(p == pp);
            if (!m) continue;                       // wave-uniform
            int cnt = __popcll(m);
            int leader = (int)__ffsll((long long)m) - 1;
            int wbase = 0;
            if (lane == leader) wbase = atomicAdd(&pcount[pp], cnt);
            wbase = __shfl(wbase, leader);
            if (p == pp) {
                int off = __popcll(m & ((1ull << lane) - 1ull));
                if (wbase + off < PCAP)             // safety clamp (never hit at these sizes)
                    parts[(size_t)pp * PCAP + wbase + off] = make_int2(s, d);
            }
        }
    }
}

// ---- exclusive scan of deg[N] -> rowptr[N+1], 1024 elems per block ----
__global__ void scan1(const int* __restrict__ deg, int N, int* __restrict__ bsum) {
    __shared__ int lsum[256];
    int t = threadIdx.x;
    int base = blockIdx.x * 1024 + t * 4;
    int s = 0;
    #pragma unroll
    for (int i = 0; i < 4; i++) { int g = base + i; s += (g < N) ? deg[g] : 0; }
    lsum[t] = s; __syncthreads();
    for (int off = 128; off > 0; off >>= 1) {
        if (t < off) lsum[t] += lsum[t + off];
        __syncthreads();
    }
    if (t == 0) bsum[blockIdx.x] = lsum[0];
}

__global__ void scan2(int* bsum, int nb, int* rowptr, int N) {
    __shared__ int A[256], B[256];
    int t = threadIdx.x;
    if (nb <= 256) {
        int v = (t < nb) ? bsum[t] : 0;
        A[t] = v; __syncthreads();
        int* in = A; int* out = B;
        for (int off = 1; off < 256; off <<= 1) {
            out[t] = in[t] + ((t >= off) ? in[t - off] : 0);
            __syncthreads();
            int* z = in; in = out; out = z;
        }
        if (t < nb) bsum[t] = in[t] - v;            // exclusive
        if (t == 0) rowptr[N] = in[255];
    } else if (t == 0) {
        int run = 0;
        for (int i = 0; i < nb; i++) { int v = bsum[i]; bsum[i] = run; run += v; }
        rowptr[N] = run;
    }
}

__global__ void scan3(const int* __restrict__ deg, int N, const int* __restrict__ boff,
                      int* __restrict__ rowptr, float* __restrict__ dinv) {
    __shared__ int A[256], B[256];
    int t = threadIdx.x;
    int base = blockIdx.x * 1024 + t * 4;
    int v[4]; int s = 0;
    #pragma unroll
    for (int i = 0; i < 4; i++) { int g = base + i; v[i] = (g < N) ? deg[g] : 0; s += v[i]; }
    A[t] = s; __syncthreads();
    int* in = A; int* out = B;
    for (int off = 1; off < 256; off <<= 1) {
        out[t] = in[t] + ((t >= off) ? in[t - off] : 0);
        __syncthreads();
        int* tmp = in; in = out; out = tmp;
    }
    int excl = (t == 0) ? 0 : in[t - 1];
    int run = boff[blockIdx.x] + excl;
    #pragma unroll
    for (int i = 0; i < 4; i++) {
        int g = base + i;
        if (g < N) {
            rowptr[g] = run;
            dinv[g] = rsqrtf((float)(v[i] + 1));
        }
        run += v[i];
    }
}

// ---- place: group g reads ONLY its partition, scatters into its csr slice ----
__global__ __launch_bounds__(256) void place_edges(const int* __restrict__ pcount,
                                                   const int2* __restrict__ parts,
                                                   const int* __restrict__ rowptr,
                                                   int* __restrict__ cursor,
                                                   int* __restrict__ csr) {
    int g = blockIdx.x & 7;
    int cnt = pcount[g]; if (cnt > PCAP) cnt = PCAP;
    int gblk = blockIdx.x >> 3;
    int ngblk = gridDim.x >> 3;
    int j = gblk * blockDim.x + threadIdx.x;
    int gstride = ngblk * blockDim.x;
    const int2* pg = parts + (size_t)g * PCAP;
    for (; j < cnt; j += gstride) {
        int2 e = pg[j];
        int pos = rowptr[e.y] + atomicAdd(&cursor[e.y], 1);
        csr[pos] = e.x;
    }
}

// ---- y16[n,:] = half((x[n,:] @ W) * dinv[n]) — LDS-tiled 64x64 ----
template <typename TIN>
__global__ __launch_bounds__(256, 4) void gemm_scale(const TIN* __restrict__ x,
                                                     const float* __restrict__ W,
                                                     const float* __restrict__ dinv,
                                                     __half* __restrict__ y16, int N) {
    __shared__ float Xl[64 * 68];   // pad to 68 to break bank aliasing
    __shared__ float Wl[64 * 64];
    int t = threadIdx.x;
    int nbase = blockIdx.x * 64;
    for (int i = t; i < 1024; i += 256) {
        ((float4*)Wl)[i] = ((const float4*)W)[i];
    }
    for (int i = t; i < 1024; i += 256) {
        int flat = i * 4;
        int n = flat >> 6, k = flat & 63;
        int g = nbase + n;
        float4 v;
        if (g < N) {
            if constexpr (sizeof(TIN) == 2) {
                const __half2* hp = (const __half2*)((const __half*)x + (size_t)g * FDIM + k);
                float2 a = __half22float2(hp[0]);
                float2 c = __half22float2(hp[1]);
                v = make_float4(a.x, a.y, c.x, c.y);
            } else {
                v = *(const float4*)((const float*)x + (size_t)g * FDIM + k);
            }
        } else {
            v = make_float4(0.f, 0.f, 0.f, 0.f);
        }
        *(float4*)&Xl[n * 68 + k] = v;
    }
    __syncthreads();

    int fr = t & 15;    // feature group: feats fr*4..fr*4+3
    int ng = t >> 4;    // node group:    nodes ng*4..ng*4+3
    float acc[4][4] = {{0.f}};
    #pragma unroll 4
    for (int kc = 0; kc < 16; kc++) {
        float4 xa[4], wa[4];
        #pragma unroll
        for (int i = 0; i < 4; i++) xa[i] = *(float4*)&Xl[(ng * 4 + i) * 68 + kc * 4];
        #pragma unroll
        for (int j = 0; j < 4; j++) wa[j] = *(float4*)&Wl[(kc * 4 + j) * 64 + fr * 4];
        #pragma unroll
        for (int i = 0; i < 4; i++) {
            acc[i][0] += xa[i].x * wa[0].x + xa[i].y * wa[1].x + xa[i].z * wa[2].x + xa[i].w * wa[3].x;
            acc[i][1] += xa[i].x * wa[0].y + xa[i].y * wa[1].y + xa[i].z * wa[2].y + xa[i].w * wa[3].y;
            acc[i][2] += xa[i].x * wa[0].z + xa[i].y * wa[1].z + xa[i].z * wa[2].z + xa[i].w * wa[3].z;
            acc[i][3] += xa[i].x * wa[0].w + xa[i].y * wa[1].w + xa[i].z * wa[2].w + xa[i].w * wa[3].w;
        }
    }
    #pragma unroll
    for (int i = 0; i < 4; i++) {
        int g = nbase + ng * 4 + i;
        if (g < N) {
            float dv = dinv[g];
            __half2 ha = __floats2half2_rn(acc[i][0] * dv, acc[i][1] * dv);
            __half2 hb = __floats2half2_rn(acc[i][2] * dv, acc[i][3] * dv);
            union { __half2 h[2]; uint2 u; } cvt;
            cvt.h[0] = ha; cvt.h[1] = hb;
            *(uint2*)(y16 + (size_t)g * FDIM + fr * 4) = cvt.u;
        }
    }
}

// ---- gather: out[n,:] = dinv[n]*(y[n,:] + sum_bucket y[src,:]) + b (+ReLU) ----
// fp16 rows (128 B): lanes 0-31 take even edges, 32-63 odd edges, half2 per lane.
template <bool RELU, typename OUT_T>
__global__ __launch_bounds__(256) void gather(const int* __restrict__ rowptr,
                                              const int* __restrict__ csr,
                                              const __half* __restrict__ y16,
                                              const float* __restrict__ dinv,
                                              const float* __restrict__ b,
                                              OUT_T* __restrict__ out, int N) {
    int lane = threadIdx.x & 63;
    int n = blockIdx.x * 4 + (threadIdx.x >> 6);
    if (n >= N) return;
    int h = lane >> 5;       // edge-stream half
    int fl = lane & 31;      // feature pair index (feats 2fl, 2fl+1)
    int start = rowptr[n], end = rowptr[n + 1];
    float ax = 0.f, ay = 0.f;
    for (int base = start; base < end; base += 64) {
        int m = end - base; if (m > 64) m = 64;
        int idx = (lane < m) ? csr[base + lane] : 0;
        int j = 0;
        for (; j + 7 < m; j += 8) {
            int s0 = __shfl(idx, j + h);
            int s1 = __shfl(idx, j + 2 + h);
            int s2 = __shfl(idx, j + 4 + h);
            int s3 = __shfl(idx, j + 6 + h);
            __half2 v0 = *(const __half2*)(y16 + (size_t)s0 * FDIM + 2 * fl);
            __half2 v1 = *(const __half2*)(y16 + (size_t)s1 * FDIM + 2 * fl);
            __half2 v2 = *(const __half2*)(y16 + (size_t)s2 * FDIM + 2 * fl);
            __half2 v3 = *(const __half2*)(y16 + (size_t)s3 * FDIM + 2 * fl);
            float2 f0 = __half22float2(v0), f1 = __half22float2(v1);
            float2 f2 = __half22float2(v2), f3 = __half22float2(v3);
            ax += (f0.x + f1.x) + (f2.x + f3.x);
            ay += (f0.y + f1.y) + (f2.y + f3.y);
        }
        for (; j < m; j += 2) {
            int e = j + h;
            int se = __shfl(idx, (e < m) ? e : (m - 1));
            __half2 v = *(const __half2*)(y16 + (size_t)se * FDIM + 2 * fl);
            if (e < m) { float2 f = __half22float2(v); ax += f.x; ay += f.y; }
        }
    }
    // combine the two edge-stream halves
    ax += __shfl_xor(ax, 32);
    ay += __shfl_xor(ay, 32);
    if (h == 0) {
        __half2 sv = *(const __half2*)(y16 + (size_t)n * FDIM + 2 * fl);   // self loop
        float2 sf = __half22float2(sv);
        float dv = dinv[n];
        float2 bb = ((const float2*)b)[fl];
        float ox = (ax + sf.x) * dv + bb.x;
        float oy = (ay + sf.y) * dv + bb.y;
        if (RELU) { ox = fmaxf(ox, 0.f); oy = fmaxf(oy, 0.f); }
        if constexpr (sizeof(OUT_T) == 2) {
            *(__half2*)((__half*)out + (size_t)n * FDIM + 2 * fl) = __floats2half2_rn(ox, oy);
        } else {
            *(float2*)((float*)out + (size_t)n * FDIM + 2 * fl) = make_float2(ox, oy);
        }
    }
}

static inline size_t roundup256(size_t x) { return (x + 255) & ~(size_t)255; }

extern "C" void kernel_launch(void* const* d_in, const int* in_sizes, int n_in,
                              void* d_out, int out_size, void* d_ws, size_t ws_size,
                              hipStream_t stream) {
    const float* x  = (const float*)d_in[0];
    const void*  ei = d_in[1];
    const float* W1 = (const float*)d_in[2];
    const float* b1 = (const float*)d_in[3];
    const float* W2 = (const float*)d_in[4];
    const float* b2 = (const float*)d_in[5];
    float* out = (float*)d_out;

    int N = out_size / FDIM;          // 100000
    int E = in_sizes[1] / 2;          // 1200000
    int NB = (N + 1023) / 1024;       // scan blocks (98)

    // ws layout (256B-aligned slots)
    char* p = (char*)d_ws;
    float* dinv  = (float*)p;  p += roundup256((size_t)N * 4);
    __half* y16  = (__half*)p; p += roundup256((size_t)N * FDIM * 2);
    __half* h16  = (__half*)p; p += roundup256((size_t)N * FDIM * 2);
    int* deg     = (int*)p;    p += roundup256((size_t)N * 4);
    int* cursor  = (int*)p;    p += roundup256((size_t)N * 4);
    int* pcount  = (int*)p;    p += 256;
    int* flag    = (int*)p;    p += 256;
    int* rowptr  = (int*)p;    p += roundup256((size_t)(N + 1) * 4);
    int* bsum    = (int*)p;    p += 1024;
    int* csr     = (int*)p;    p += roundup256((size_t)E * 4);
    int2* parts  = (int2*)p;   p += (size_t)8 * PCAP * sizeof(int2);

    // zero deg+cursor+pcount in one memset (contiguous slots)
    size_t zlen = (size_t)((char*)pcount + 256 - (char*)deg);
    hipMemsetAsync(deg, 0, zlen, stream);

    // ---- graph prep ----
    detect_dtype_kernel<<<1, 256, 0, stream>>>((const int*)ei, 2048, flag);
    convert_partition<<<2048, 256, 0, stream>>>(ei, flag, E, deg, pcount, parts);
    scan1<<<NB, 256, 0, stream>>>(deg, N, bsum);
    scan2<<<1, 256, 0, stream>>>(bsum, NB, rowptr, N);
    scan3<<<NB, 256, 0, stream>>>(deg, N, bsum, rowptr, dinv);
    place_edges<<<2048, 256, 0, stream>>>(pcount, parts, rowptr, cursor, csr);

    int gemm_grid = (N + 63) / 64;
    int gath_grid = (N + 3) / 4;

    // ---- layer 1: h = relu(GCNConv(x, W1, b1)) -> h16 (fp16) ----
    gemm_scale<float><<<gemm_grid, 256, 0, stream>>>(x, W1, dinv, y16, N);
    gather<true, __half><<<gath_grid, 256, 0, stream>>>(rowptr, csr, y16, dinv, b1, h16, N);

    // ---- layer 2: out = GCNConv(h, W2, b2) -> fp32 d_out ----
    gemm_scale<__half><<<gemm_grid, 256, 0, stream>>>(h16, W2, dinv, y16, N);
    gather<false, float><<<gath_grid, 256, 0, stream>>>(rowptr, csr, y16, dinv, b2, out, N);
}

// Round 6
// 260.938 us; speedup vs baseline: 7.3440x; 7.3440x over previous
//
#include <hip/hip_runtime.h>
#include <hip/hip_fp16.h>

#define FDIM 64
#define PCAP 400000   // per-partition capacity (expected ~190K max, 2x headroom)

// ---- detect whether edge_index is int64 (high dwords all zero) or int32 ----
__global__ void detect_dtype_kernel(const int* ei, int nsamp, int* flag) {
    __shared__ int any_nz;
    if (threadIdx.x == 0) any_nz = 0;
    __syncthreads();
    int local = 0;
    for (int i = threadIdx.x; i < nsamp; i += blockDim.x) {
        if (ei[2 * i + 1] != 0) local = 1;   // odd dword: int64 high word (==0) vs real int32 index
    }
    if (local) atomicOr(&any_nz, 1);
    __syncthreads();
    if (threadIdx.x == 0) flag[0] = (any_nz == 0) ? 1 : 0;   // 1 => int64
}

// ---- single pass: convert, count deg, partition into 8 XCD-group streams.
// Block-aggregated reservation: per-thread LDS atomics for local offsets,
// then only 8 GLOBAL atomics per 1024-edge batch (threads 0-7). ----
__global__ __launch_bounds__(256) void convert_partition(const void* ei, const int* flag, int E,
                                                         int* __restrict__ deg,
                                                         int* __restrict__ pcount,
                                                         int2* __restrict__ parts) {
    __shared__ int lcnt[8];
    __shared__ int lbase[8];
    int is64 = flag[0];
    int t = threadIdx.x;
    int nbatch = (E + 1023) >> 10;
    for (int bb = blockIdx.x; bb < nbatch; bb += gridDim.x) {
        int base = bb << 10;
        if (t < 8) lcnt[t] = 0;
        __syncthreads();
        int sv[4], dv[4], pv[4], lo[4];
        bool val[4];
        #pragma unroll
        for (int u = 0; u < 4; u++) {
            int i = base + u * 256 + t;          // coalesced within each u-step
            val[u] = i < E;
            if (val[u]) {
                if (is64) {
                    const long long* q = (const long long*)ei;
                    sv[u] = (int)q[i]; dv[u] = (int)q[E + i];
                } else {
                    const int* q = (const int*)ei;
                    sv[u] = q[i]; dv[u] = q[E + i];
                }
                pv[u] = (dv[u] >> 12) & 7;
                lo[u] = atomicAdd(&lcnt[pv[u]], 1);   // LDS atomic: block-local offset
                atomicAdd(&deg[dv[u]], 1);
            }
        }
        __syncthreads();
        if (t < 8) lbase[t] = atomicAdd(&pcount[t], lcnt[t]);   // 8 global atomics/batch
        __syncthreads();
        #pragma unroll
        for (int u = 0; u < 4; u++) {
            if (val[u]) {
                int pos = lbase[pv[u]] + lo[u];
                if (pos < PCAP)
                    parts[(size_t)pv[u] * PCAP + pos] = make_int2(sv[u], dv[u]);
            }
        }
        __syncthreads();   // protect lcnt re-zero of next batch
    }
}

// ---- exclusive scan of deg[N] -> rowptr[N+1], 1024 elems per block ----
__global__ void scan1(const int* __restrict__ deg, int N, int* __restrict__ bsum) {
    __shared__ int lsum[256];
    int t = threadIdx.x;
    int base = blockIdx.x * 1024 + t * 4;
    int s = 0;
    #pragma unroll
    for (int i = 0; i < 4; i++) { int g = base + i; s += (g < N) ? deg[g] : 0; }
    lsum[t] = s; __syncthreads();
    for (int off = 128; off > 0; off >>= 1) {
        if (t < off) lsum[t] += lsum[t + off];
        __syncthreads();
    }
    if (t == 0) bsum[blockIdx.x] = lsum[0];
}

__global__ void scan2(int* bsum, int nb, int* rowptr, int N) {
    __shared__ int A[256], B[256];
    int t = threadIdx.x;
    if (nb <= 256) {
        int v = (t < nb) ? bsum[t] : 0;
        A[t] = v; __syncthreads();
        int* in = A; int* out = B;
        for (int off = 1; off < 256; off <<= 1) {
            out[t] = in[t] + ((t >= off) ? in[t - off] : 0);
            __syncthreads();
            int* z = in; in = out; out = z;
        }
        if (t < nb) bsum[t] = in[t] - v;            // exclusive
        if (t == 0) rowptr[N] = in[255];
    } else if (t == 0) {
        int run = 0;
        for (int i = 0; i < nb; i++) { int v = bsum[i]; bsum[i] = run; run += v; }
        rowptr[N] = run;
    }
}

__global__ void scan3(const int* __restrict__ deg, int N, const int* __restrict__ boff,
                      int* __restrict__ rowptr, float* __restrict__ dinv) {
    __shared__ int A[256], B[256];
    int t = threadIdx.x;
    int base = blockIdx.x * 1024 + t * 4;
    int v[4]; int s = 0;
    #pragma unroll
    for (int i = 0; i < 4; i++) { int g = base + i; v[i] = (g < N) ? deg[g] : 0; s += v[i]; }
    A[t] = s; __syncthreads();
    int* in = A; int* out = B;
    for (int off = 1; off < 256; off <<= 1) {
        out[t] = in[t] + ((t >= off) ? in[t - off] : 0);
        __syncthreads();
        int* tmp = in; in = out; out = tmp;
    }
    int excl = (t == 0) ? 0 : in[t - 1];
    int run = boff[blockIdx.x] + excl;
    #pragma unroll
    for (int i = 0; i < 4; i++) {
        int g = base + i;
        if (g < N) {
            rowptr[g] = run;
            dinv[g] = rsqrtf((float)(v[i] + 1));
        }
        run += v[i];
    }
}

// ---- place: group g reads ONLY its partition, scatters into its csr slice ----
__global__ __launch_bounds__(256) void place_edges(const int* __restrict__ pcount,
                                                   const int2* __restrict__ parts,
                                                   const int* __restrict__ rowptr,
                                                   int* __restrict__ cursor,
                                                   int* __restrict__ csr) {
    int g = blockIdx.x & 7;
    int cnt = pcount[g]; if (cnt > PCAP) cnt = PCAP;
    int gblk = blockIdx.x >> 3;
    int ngblk = gridDim.x >> 3;
    int j = gblk * blockDim.x + threadIdx.x;
    int gstride = ngblk * blockDim.x;
    const int2* pg = parts + (size_t)g * PCAP;
    for (; j < cnt; j += gstride) {
        int2 e = pg[j];
        int pos = rowptr[e.y] + atomicAdd(&cursor[e.y], 1);
        csr[pos] = e.x;
    }
}

// ---- y16[n,:] = half((x[n,:] @ W) * dinv[n]) — LDS-tiled 64x64 ----
template <typename TIN>
__global__ __launch_bounds__(256, 4) void gemm_scale(const TIN* __restrict__ x,
                                                     const float* __restrict__ W,
                                                     const float* __restrict__ dinv,
                                                     __half* __restrict__ y16, int N) {
    __shared__ float Xl[64 * 68];   // pad to 68 to break bank aliasing
    __shared__ float Wl[64 * 64];
    int t = threadIdx.x;
    int nbase = blockIdx.x * 64;
    for (int i = t; i < 1024; i += 256) {
        ((float4*)Wl)[i] = ((const float4*)W)[i];
    }
    for (int i = t; i < 1024; i += 256) {
        int flat = i * 4;
        int n = flat >> 6, k = flat & 63;
        int g = nbase + n;
        float4 v;
        if (g < N) {
            if constexpr (sizeof(TIN) == 2) {
                const __half2* hp = (const __half2*)((const __half*)x + (size_t)g * FDIM + k);
                float2 a = __half22float2(hp[0]);
                float2 c = __half22float2(hp[1]);
                v = make_float4(a.x, a.y, c.x, c.y);
            } else {
                v = *(const float4*)((const float*)x + (size_t)g * FDIM + k);
            }
        } else {
            v = make_float4(0.f, 0.f, 0.f, 0.f);
        }
        *(float4*)&Xl[n * 68 + k] = v;
    }
    __syncthreads();

    int fr = t & 15;    // feature group: feats fr*4..fr*4+3
    int ng = t >> 4;    // node group:    nodes ng*4..ng*4+3
    float acc[4][4] = {{0.f}};
    #pragma unroll 4
    for (int kc = 0; kc < 16; kc++) {
        float4 xa[4], wa[4];
        #pragma unroll
        for (int i = 0; i < 4; i++) xa[i] = *(float4*)&Xl[(ng * 4 + i) * 68 + kc * 4];
        #pragma unroll
        for (int j = 0; j < 4; j++) wa[j] = *(float4*)&Wl[(kc * 4 + j) * 64 + fr * 4];
        #pragma unroll
        for (int i = 0; i < 4; i++) {
            acc[i][0] += xa[i].x * wa[0].x + xa[i].y * wa[1].x + xa[i].z * wa[2].x + xa[i].w * wa[3].x;
            acc[i][1] += xa[i].x * wa[0].y + xa[i].y * wa[1].y + xa[i].z * wa[2].y + xa[i].w * wa[3].y;
            acc[i][2] += xa[i].x * wa[0].z + xa[i].y * wa[1].z + xa[i].z * wa[2].z + xa[i].w * wa[3].z;
            acc[i][3] += xa[i].x * wa[0].w + xa[i].y * wa[1].w + xa[i].z * wa[2].w + xa[i].w * wa[3].w;
        }
    }
    #pragma unroll
    for (int i = 0; i < 4; i++) {
        int g = nbase + ng * 4 + i;
        if (g < N) {
            float dv = dinv[g];
            __half2 ha = __floats2half2_rn(acc[i][0] * dv, acc[i][1] * dv);
            __half2 hb = __floats2half2_rn(acc[i][2] * dv, acc[i][3] * dv);
            union { __half2 h[2]; uint2 u; } cvt;
            cvt.h[0] = ha; cvt.h[1] = hb;
            *(uint2*)(y16 + (size_t)g * FDIM + fr * 4) = cvt.u;
        }
    }
}

// ---- gather: out[n,:] = dinv[n]*(y[n,:] + sum_bucket y[src,:]) + b (+ReLU) ----
// fp16 rows (128 B): lanes 0-31 take even edges, 32-63 odd edges, half2 per lane.
template <bool RELU, typename OUT_T>
__global__ __launch_bounds__(256) void gather(const int* __restrict__ rowptr,
                                              const int* __restrict__ csr,
                                              const __half* __restrict__ y16,
                                              const float* __restrict__ dinv,
                                              const float* __restrict__ b,
                                              OUT_T* __restrict__ out, int N) {
    int lane = threadIdx.x & 63;
    int n = blockIdx.x * 4 + (threadIdx.x >> 6);
    if (n >= N) return;
    int h = lane >> 5;       // edge-stream half
    int fl = lane & 31;      // feature pair index (feats 2fl, 2fl+1)
    int start = rowptr[n], end = rowptr[n + 1];
    float ax = 0.f, ay = 0.f;
    for (int base = start; base < end; base += 64) {
        int m = end - base; if (m > 64) m = 64;
        int idx = (lane < m) ? csr[base + lane] : 0;
        int j = 0;
        for (; j + 7 < m; j += 8) {
            int s0 = __shfl(idx, j + h);
            int s1 = __shfl(idx, j + 2 + h);
            int s2 = __shfl(idx, j + 4 + h);
            int s3 = __shfl(idx, j + 6 + h);
            __half2 v0 = *(const __half2*)(y16 + (size_t)s0 * FDIM + 2 * fl);
            __half2 v1 = *(const __half2*)(y16 + (size_t)s1 * FDIM + 2 * fl);
            __half2 v2 = *(const __half2*)(y16 + (size_t)s2 * FDIM + 2 * fl);
            __half2 v3 = *(const __half2*)(y16 + (size_t)s3 * FDIM + 2 * fl);
            float2 f0 = __half22float2(v0), f1 = __half22float2(v1);
            float2 f2 = __half22float2(v2), f3 = __half22float2(v3);
            ax += (f0.x + f1.x) + (f2.x + f3.x);
            ay += (f0.y + f1.y) + (f2.y + f3.y);
        }
        for (; j < m; j += 2) {
            int e = j + h;
            int se = __shfl(idx, (e < m) ? e : (m - 1));
            __half2 v = *(const __half2*)(y16 + (size_t)se * FDIM + 2 * fl);
            if (e < m) { float2 f = __half22float2(v); ax += f.x; ay += f.y; }
        }
    }
    // combine the two edge-stream halves
    ax += __shfl_xor(ax, 32);
    ay += __shfl_xor(ay, 32);
    if (h == 0) {
        __half2 sv = *(const __half2*)(y16 + (size_t)n * FDIM + 2 * fl);   // self loop
        float2 sf = __half22float2(sv);
        float dv = dinv[n];
        float2 bb = ((const float2*)b)[fl];
        float ox = (ax + sf.x) * dv + bb.x;
        float oy = (ay + sf.y) * dv + bb.y;
        if (RELU) { ox = fmaxf(ox, 0.f); oy = fmaxf(oy, 0.f); }
        if constexpr (sizeof(OUT_T) == 2) {
            *(__half2*)((__half*)out + (size_t)n * FDIM + 2 * fl) = __floats2half2_rn(ox, oy);
        } else {
            *(float2*)((float*)out + (size_t)n * FDIM + 2 * fl) = make_float2(ox, oy);
        }
    }
}

static inline size_t roundup256(size_t x) { return (x + 255) & ~(size_t)255; }

extern "C" void kernel_launch(void* const* d_in, const int* in_sizes, int n_in,
                              void* d_out, int out_size, void* d_ws, size_t ws_size,
                              hipStream_t stream) {
    const float* x  = (const float*)d_in[0];
    const void*  ei = d_in[1];
    const float* W1 = (const float*)d_in[2];
    const float* b1 = (const float*)d_in[3];
    const float* W2 = (const float*)d_in[4];
    const float* b2 = (const float*)d_in[5];
    float* out = (float*)d_out;

    int N = out_size / FDIM;          // 100000
    int E = in_sizes[1] / 2;          // 1200000
    int NB = (N + 1023) / 1024;       // scan blocks (98)
    int NBATCH = (E + 1023) >> 10;    // convert batches (1172)

    // ws layout (256B-aligned slots)
    char* p = (char*)d_ws;
    float* dinv  = (float*)p;  p += roundup256((size_t)N * 4);
    __half* y16  = (__half*)p; p += roundup256((size_t)N * FDIM * 2);
    __half* h16  = (__half*)p; p += roundup256((size_t)N * FDIM * 2);
    int* deg     = (int*)p;    p += roundup256((size_t)N * 4);
    int* cursor  = (int*)p;    p += roundup256((size_t)N * 4);
    int* pcount  = (int*)p;    p += 256;
    int* flag    = (int*)p;    p += 256;
    int* rowptr  = (int*)p;    p += roundup256((size_t)(N + 1) * 4);
    int* bsum    = (int*)p;    p += 1024;
    int* csr     = (int*)p;    p += roundup256((size_t)E * 4);
    int2* parts  = (int2*)p;   p += (size_t)8 * PCAP * sizeof(int2);

    // zero deg+cursor+pcount in one memset (contiguous slots)
    size_t zlen = (size_t)((char*)pcount + 256 - (char*)deg);
    hipMemsetAsync(deg, 0, zlen, stream);

    // ---- graph prep ----
    detect_dtype_kernel<<<1, 256, 0, stream>>>((const int*)ei, 2048, flag);
    convert_partition<<<NBATCH, 256, 0, stream>>>(ei, flag, E, deg, pcount, parts);
    scan1<<<NB, 256, 0, stream>>>(deg, N, bsum);
    scan2<<<1, 256, 0, stream>>>(bsum, NB, rowptr, N);
    scan3<<<NB, 256, 0, stream>>>(deg, N, bsum, rowptr, dinv);
    place_edges<<<2048, 256, 0, stream>>>(pcount, parts, rowptr, cursor, csr);

    int gemm_grid = (N + 63) / 64;
    int gath_grid = (N + 3) / 4;

    // ---- layer 1: h = relu(GCNConv(x, W1, b1)) -> h16 (fp16) ----
    gemm_scale<float><<<gemm_grid, 256, 0, stream>>>(x, W1, dinv, y16, N);
    gather<true, __half><<<gath_grid, 256, 0, stream>>>(rowptr, csr, y16, dinv, b1, h16, N);

    // ---- layer 2: out = GCNConv(h, W2, b2) -> fp32 d_out ----
    gemm_scale<__half><<<gemm_grid, 256, 0, stream>>>(h16, W2, dinv, y16, N);
    gather<false, float><<<gath_grid, 256, 0, stream>>>(rowptr, csr, y16, dinv, b2, out, N);
}

// Round 7
// 258.651 us; speedup vs baseline: 7.4089x; 1.0088x over previous
//
#include <hip/hip_runtime.h>
#include <hip/hip_fp16.h>

#define FDIM 64
#define PCAP 400000   // per-partition capacity (expected ~190K max, 2x headroom)

// ---- detect whether edge_index is int64 (high dwords all zero) or int32 ----
__global__ void detect_dtype_kernel(const int* ei, int nsamp, int* flag) {
    __shared__ int any_nz;
    if (threadIdx.x == 0) any_nz = 0;
    __syncthreads();
    int local = 0;
    for (int i = threadIdx.x; i < nsamp; i += blockDim.x) {
        if (ei[2 * i + 1] != 0) local = 1;   // odd dword: int64 high word (==0) vs real int32 index
    }
    if (local) atomicOr(&any_nz, 1);
    __syncthreads();
    if (threadIdx.x == 0) flag[0] = (any_nz == 0) ? 1 : 0;   // 1 => int64
}

// ---- single pass: convert, count deg, partition into 8 XCD-group streams.
// Reduction pyramid: lane -> wave (ballot/popc, register-only) -> block (8 LDS
// atomics per wave per u-step) -> global (8 atomics per batch). ----
__global__ __launch_bounds__(256) void convert_partition(const void* ei, const int* flag, int E,
                                                         int* __restrict__ deg,
                                                         int* __restrict__ pcount,
                                                         int2* __restrict__ parts) {
    __shared__ int lcnt[8];
    __shared__ int lbase[8];
    int is64 = flag[0];
    int t = threadIdx.x;
    int lane = t & 63;
    int nbatch = (E + 1023) >> 10;
    for (int bb = blockIdx.x; bb < nbatch; bb += gridDim.x) {
        int base = bb << 10;
        if (t < 8) lcnt[t] = 0;
        __syncthreads();
        int sv[4], dv[4], pv[4], lo[4];
        bool val[4];
        #pragma unroll
        for (int u = 0; u < 4; u++) {
            int i = base + u * 256 + t;          // coalesced within each u-step
            val[u] = i < E;
            sv[u] = 0; dv[u] = 0; lo[u] = 0;
            if (val[u]) {
                if (is64) {
                    const long long* q = (const long long*)ei;
                    sv[u] = (int)q[i]; dv[u] = (int)q[E + i];
                } else {
                    const int* q = (const int*)ei;
                    sv[u] = q[i]; dv[u] = q[E + i];
                }
                atomicAdd(&deg[dv[u]], 1);
            }
            pv[u] = val[u] ? ((dv[u] >> 12) & 7) : -1;
            // wave-aggregated reservation: 1 LDS atomic per wave per partition
            #pragma unroll
            for (int pp = 0; pp < 8; pp++) {
                unsigned long long mk = __ballot(pv[u] == pp);
                if (mk) {                         // wave-uniform branch
                    int leader = (int)__ffsll(mk) - 1;
                    int wb = 0;
                    if (lane == leader) wb = atomicAdd(&lcnt[pp], __popcll(mk));
                    wb = __shfl(wb, leader);
                    if (pv[u] == pp)
                        lo[u] = wb + (int)__popcll(mk & ((1ull << lane) - 1ull));
                }
            }
        }
        __syncthreads();
        if (t < 8) lbase[t] = atomicAdd(&pcount[t], lcnt[t]);   // 8 global atomics/batch
        __syncthreads();
        #pragma unroll
        for (int u = 0; u < 4; u++) {
            if (val[u]) {
                int pos = lbase[pv[u]] + lo[u];
                if (pos < PCAP)
                    parts[(size_t)pv[u] * PCAP + pos] = make_int2(sv[u], dv[u]);
            }
        }
        __syncthreads();   // protect lcnt re-zero of next batch
    }
}

// ---- exclusive scan of deg[N] -> rowptr[N+1], 1024 elems per block ----
__global__ void scan1(const int* __restrict__ deg, int N, int* __restrict__ bsum) {
    __shared__ int lsum[256];
    int t = threadIdx.x;
    int base = blockIdx.x * 1024 + t * 4;
    int s = 0;
    #pragma unroll
    for (int i = 0; i < 4; i++) { int g = base + i; s += (g < N) ? deg[g] : 0; }
    lsum[t] = s; __syncthreads();
    for (int off = 128; off > 0; off >>= 1) {
        if (t < off) lsum[t] += lsum[t + off];
        __syncthreads();
    }
    if (t == 0) bsum[blockIdx.x] = lsum[0];
}

__global__ void scan2(int* bsum, int nb, int* rowptr, int N) {
    __shared__ int A[256], B[256];
    int t = threadIdx.x;
    if (nb <= 256) {
        int v = (t < nb) ? bsum[t] : 0;
        A[t] = v; __syncthreads();
        int* in = A; int* out = B;
        for (int off = 1; off < 256; off <<= 1) {
            out[t] = in[t] + ((t >= off) ? in[t - off] : 0);
            __syncthreads();
            int* z = in; in = out; out = z;
        }
        if (t < nb) bsum[t] = in[t] - v;            // exclusive
        if (t == 0) rowptr[N] = in[255];
    } else if (t == 0) {
        int run = 0;
        for (int i = 0; i < nb; i++) { int v = bsum[i]; bsum[i] = run; run += v; }
        rowptr[N] = run;
    }
}

__global__ void scan3(const int* __restrict__ deg, int N, const int* __restrict__ boff,
                      int* __restrict__ rowptr, float* __restrict__ dinv) {
    __shared__ int A[256], B[256];
    int t = threadIdx.x;
    int base = blockIdx.x * 1024 + t * 4;
    int v[4]; int s = 0;
    #pragma unroll
    for (int i = 0; i < 4; i++) { int g = base + i; v[i] = (g < N) ? deg[g] : 0; s += v[i]; }
    A[t] = s; __syncthreads();
    int* in = A; int* out = B;
    for (int off = 1; off < 256; off <<= 1) {
        out[t] = in[t] + ((t >= off) ? in[t - off] : 0);
        __syncthreads();
        int* tmp = in; in = out; out = tmp;
    }
    int excl = (t == 0) ? 0 : in[t - 1];
    int run = boff[blockIdx.x] + excl;
    #pragma unroll
    for (int i = 0; i < 4; i++) {
        int g = base + i;
        if (g < N) {
            rowptr[g] = run;
            dinv[g] = rsqrtf((float)(v[i] + 1));
        }
        run += v[i];
    }
}

// ---- place: group g reads ONLY its partition, scatters into its csr slice ----
__global__ __launch_bounds__(256) void place_edges(const int* __restrict__ pcount,
                                                   const int2* __restrict__ parts,
                                                   const int* __restrict__ rowptr,
                                                   int* __restrict__ cursor,
                                                   int* __restrict__ csr) {
    int g = blockIdx.x & 7;
    int cnt = pcount[g]; if (cnt > PCAP) cnt = PCAP;
    int gblk = blockIdx.x >> 3;
    int ngblk = gridDim.x >> 3;
    int j = gblk * blockDim.x + threadIdx.x;
    int gstride = ngblk * blockDim.x;
    const int2* pg = parts + (size_t)g * PCAP;
    for (; j < cnt; j += gstride) {
        int2 e = pg[j];
        int pos = rowptr[e.y] + atomicAdd(&cursor[e.y], 1);
        csr[pos] = e.x;
    }
}

// ---- y16[n,:] = half((x[n,:] @ W) * dinv[n]) — LDS-tiled 64x64 ----
template <typename TIN>
__global__ __launch_bounds__(256, 4) void gemm_scale(const TIN* __restrict__ x,
                                                     const float* __restrict__ W,
                                                     const float* __restrict__ dinv,
                                                     __half* __restrict__ y16, int N) {
    __shared__ float Xl[64 * 68];   // pad to 68 to break bank aliasing
    __shared__ float Wl[64 * 64];
    int t = threadIdx.x;
    int nbase = blockIdx.x * 64;
    for (int i = t; i < 1024; i += 256) {
        ((float4*)Wl)[i] = ((const float4*)W)[i];
    }
    for (int i = t; i < 1024; i += 256) {
        int flat = i * 4;
        int n = flat >> 6, k = flat & 63;
        int g = nbase + n;
        float4 v;
        if (g < N) {
            if constexpr (sizeof(TIN) == 2) {
                const __half2* hp = (const __half2*)((const __half*)x + (size_t)g * FDIM + k);
                float2 a = __half22float2(hp[0]);
                float2 c = __half22float2(hp[1]);
                v = make_float4(a.x, a.y, c.x, c.y);
            } else {
                v = *(const float4*)((const float*)x + (size_t)g * FDIM + k);
            }
        } else {
            v = make_float4(0.f, 0.f, 0.f, 0.f);
        }
        *(float4*)&Xl[n * 68 + k] = v;
    }
    __syncthreads();

    int fr = t & 15;    // feature group: feats fr*4..fr*4+3
    int ng = t >> 4;    // node group:    nodes ng*4..ng*4+3
    float acc[4][4] = {{0.f}};
    #pragma unroll 4
    for (int kc = 0; kc < 16; kc++) {
        float4 xa[4], wa[4];
        #pragma unroll
        for (int i = 0; i < 4; i++) xa[i] = *(float4*)&Xl[(ng * 4 + i) * 68 + kc * 4];
        #pragma unroll
        for (int j = 0; j < 4; j++) wa[j] = *(float4*)&Wl[(kc * 4 + j) * 64 + fr * 4];
        #pragma unroll
        for (int i = 0; i < 4; i++) {
            acc[i][0] += xa[i].x * wa[0].x + xa[i].y * wa[1].x + xa[i].z * wa[2].x + xa[i].w * wa[3].x;
            acc[i][1] += xa[i].x * wa[0].y + xa[i].y * wa[1].y + xa[i].z * wa[2].y + xa[i].w * wa[3].y;
            acc[i][2] += xa[i].x * wa[0].z + xa[i].y * wa[1].z + xa[i].z * wa[2].z + xa[i].w * wa[3].z;
            acc[i][3] += xa[i].x * wa[0].w + xa[i].y * wa[1].w + xa[i].z * wa[2].w + xa[i].w * wa[3].w;
        }
    }
    #pragma unroll
    for (int i = 0; i < 4; i++) {
        int g = nbase + ng * 4 + i;
        if (g < N) {
            float dv = dinv[g];
            __half2 ha = __floats2half2_rn(acc[i][0] * dv, acc[i][1] * dv);
            __half2 hb = __floats2half2_rn(acc[i][2] * dv, acc[i][3] * dv);
            union { __half2 h[2]; uint2 u; } cvt;
            cvt.h[0] = ha; cvt.h[1] = hb;
            *(uint2*)(y16 + (size_t)g * FDIM + fr * 4) = cvt.u;
        }
    }
}

__device__ __forceinline__ float4 half4_to_float4(uint2 u) {
    float2 a = __half22float2(*(__half2*)&u.x);
    float2 b = __half22float2(*(__half2*)&u.y);
    return make_float4(a.x, a.y, b.x, b.y);
}

// ---- gather: out[n,:] = dinv[n]*(y[n,:] + sum_bucket y[src,:]) + b (+ReLU) ----
// 4 edge streams x 16-lane rows: lane = 16*q + fl; each lane holds feats 4fl..4fl+3
// (uint2 = 4 halves). Streams combined via shfl_xor(16), shfl_xor(32).
template <bool RELU, typename OUT_T>
__global__ __launch_bounds__(256) void gather(const int* __restrict__ rowptr,
                                              const int* __restrict__ csr,
                                              const __half* __restrict__ y16,
                                              const float* __restrict__ dinv,
                                              const float* __restrict__ b,
                                              OUT_T* __restrict__ out, int N) {
    int lane = threadIdx.x & 63;
    int n = blockIdx.x * 4 + (threadIdx.x >> 6);
    if (n >= N) return;
    int q = lane >> 4;       // edge stream 0..3
    int fl = lane & 15;      // feature quad: feats 4fl..4fl+3
    int start = rowptr[n], end = rowptr[n + 1];
    float ax = 0.f, ay = 0.f, az = 0.f, aw = 0.f;
    for (int base = start; base < end; base += 64) {
        int m = end - base; if (m > 64) m = 64;
        int idx = (lane < m) ? csr[base + lane] : 0;
        int j = 0;
        for (; j + 7 < m; j += 8) {            // 8 edges via 2 row-loads/lane
            int s0 = __shfl(idx, j + q);
            int s1 = __shfl(idx, j + 4 + q);
            uint2 u0 = *(const uint2*)(y16 + (size_t)s0 * FDIM + 4 * fl);
            uint2 u1 = *(const uint2*)(y16 + (size_t)s1 * FDIM + 4 * fl);
            float4 f0 = half4_to_float4(u0);
            float4 f1 = half4_to_float4(u1);
            ax += f0.x + f1.x; ay += f0.y + f1.y;
            az += f0.z + f1.z; aw += f0.w + f1.w;
        }
        for (; j < m; j += 4) {                // tail: up to 4 edges, 1 load/lane
            int e = j + q;
            int se = __shfl(idx, (e < m) ? e : 0);
            uint2 u = *(const uint2*)(y16 + (size_t)se * FDIM + 4 * fl);
            if (e < m) {
                float4 f = half4_to_float4(u);
                ax += f.x; ay += f.y; az += f.z; aw += f.w;
            }
        }
    }
    // combine the 4 edge streams (lanes fl, fl+16, fl+32, fl+48)
    ax += __shfl_xor(ax, 16); ay += __shfl_xor(ay, 16);
    az += __shfl_xor(az, 16); aw += __shfl_xor(aw, 16);
    ax += __shfl_xor(ax, 32); ay += __shfl_xor(ay, 32);
    az += __shfl_xor(az, 32); aw += __shfl_xor(aw, 32);
    if (q == 0) {
        uint2 su = *(const uint2*)(y16 + (size_t)n * FDIM + 4 * fl);   // self loop
        float4 sf = half4_to_float4(su);
        float dv = dinv[n];
        float4 bb = ((const float4*)b)[fl];
        float ox = (ax + sf.x) * dv + bb.x;
        float oy = (ay + sf.y) * dv + bb.y;
        float oz = (az + sf.z) * dv + bb.z;
        float ow = (aw + sf.w) * dv + bb.w;
        if (RELU) {
            ox = fmaxf(ox, 0.f); oy = fmaxf(oy, 0.f);
            oz = fmaxf(oz, 0.f); ow = fmaxf(ow, 0.f);
        }
        if constexpr (sizeof(OUT_T) == 2) {
            union { __half2 h[2]; uint2 u; } cvt;
            cvt.h[0] = __floats2half2_rn(ox, oy);
            cvt.h[1] = __floats2half2_rn(oz, ow);
            *(uint2*)((__half*)out + (size_t)n * FDIM + 4 * fl) = cvt.u;
        } else {
            *(float4*)((float*)out + (size_t)n * FDIM + 4 * fl) = make_float4(ox, oy, oz, ow);
        }
    }
}

static inline size_t roundup256(size_t x) { return (x + 255) & ~(size_t)255; }

extern "C" void kernel_launch(void* const* d_in, const int* in_sizes, int n_in,
                              void* d_out, int out_size, void* d_ws, size_t ws_size,
                              hipStream_t stream) {
    const float* x  = (const float*)d_in[0];
    const void*  ei = d_in[1];
    const float* W1 = (const float*)d_in[2];
    const float* b1 = (const float*)d_in[3];
    const float* W2 = (const float*)d_in[4];
    const float* b2 = (const float*)d_in[5];
    float* out = (float*)d_out;

    int N = out_size / FDIM;          // 100000
    int E = in_sizes[1] / 2;          // 1200000
    int NB = (N + 1023) / 1024;       // scan blocks (98)
    int NBATCH = (E + 1023) >> 10;    // convert batches (1172)

    // ws layout (256B-aligned slots)
    char* p = (char*)d_ws;
    float* dinv  = (float*)p;  p += roundup256((size_t)N * 4);
    __half* y16  = (__half*)p; p += roundup256((size_t)N * FDIM * 2);
    __half* h16  = (__half*)p; p += roundup256((size_t)N * FDIM * 2);
    int* deg     = (int*)p;    p += roundup256((size_t)N * 4);
    int* cursor  = (int*)p;    p += roundup256((size_t)N * 4);
    int* pcount  = (int*)p;    p += 256;
    int* flag    = (int*)p;    p += 256;
    int* rowptr  = (int*)p;    p += roundup256((size_t)(N + 1) * 4);
    int* bsum    = (int*)p;    p += 1024;
    int* csr     = (int*)p;    p += roundup256((size_t)E * 4);
    int2* parts  = (int2*)p;   p += (size_t)8 * PCAP * sizeof(int2);

    // zero deg+cursor+pcount in one memset (contiguous slots)
    size_t zlen = (size_t)((char*)pcount + 256 - (char*)deg);
    hipMemsetAsync(deg, 0, zlen, stream);

    // ---- graph prep ----
    detect_dtype_kernel<<<1, 256, 0, stream>>>((const int*)ei, 2048, flag);
    convert_partition<<<NBATCH, 256, 0, stream>>>(ei, flag, E, deg, pcount, parts);
    scan1<<<NB, 256, 0, stream>>>(deg, N, bsum);
    scan2<<<1, 256, 0, stream>>>(bsum, NB, rowptr, N);
    scan3<<<NB, 256, 0, stream>>>(deg, N, bsum, rowptr, dinv);
    place_edges<<<2048, 256, 0, stream>>>(pcount, parts, rowptr, cursor, csr);

    int gemm_grid = (N + 63) / 64;
    int gath_grid = (N + 3) / 4;

    // ---- layer 1: h = relu(GCNConv(x, W1, b1)) -> h16 (fp16) ----
    gemm_scale<float><<<gemm_grid, 256, 0, stream>>>(x, W1, dinv, y16, N);
    gather<true, __half><<<gath_grid, 256, 0, stream>>>(rowptr, csr, y16, dinv, b1, h16, N);

    // ---- layer 2: out = GCNConv(h, W2, b2) -> fp32 d_out ----
    gemm_scale<__half><<<gemm_grid, 256, 0, stream>>>(h16, W2, dinv, y16, N);
    gather<false, float><<<gath_grid, 256, 0, stream>>>(rowptr, csr, y16, dinv, b2, out, N);
}

// Round 8
// 256.912 us; speedup vs baseline: 7.4591x; 1.0068x over previous
//
#include <hip/hip_runtime.h>
#include <hip/hip_fp16.h>

#define FDIM 64
#define PCAP 400000    // per-partition capacity (expected ~190K max, 2x headroom)
#define PSTRIDE 32     // ints between partition counters (128 B = own cache line)
#define CBATCH 2048    // edges per batch
#define NU (CBATCH / 256)

// ---- detect whether edge_index is int64 (high dwords all zero) or int32 ----
__global__ void detect_dtype_kernel(const int* ei, int nsamp, int* flag) {
    __shared__ int any_nz;
    if (threadIdx.x == 0) any_nz = 0;
    __syncthreads();
    int local = 0;
    for (int i = threadIdx.x; i < nsamp; i += blockDim.x) {
        if (ei[2 * i + 1] != 0) local = 1;   // odd dword: int64 high word (==0) vs real int32 index
    }
    if (local) atomicOr(&any_nz, 1);
    __syncthreads();
    if (threadIdx.x == 0) flag[0] = (any_nz == 0) ? 1 : 0;   // 1 => int64
}

// ---- single pass: convert, count deg, partition into 8 XCD-group streams.
// Reduction pyramid: lane -> wave (ballot, regs) -> block (LDS) -> global
// (8 PADDED counters, one line each; 586 atomics per counter total). ----
__global__ __launch_bounds__(256) void convert_partition(const void* ei, const int* flag, int E,
                                                         int* __restrict__ deg,
                                                         int* __restrict__ pcount,
                                                         int2* __restrict__ parts) {
    __shared__ int lcnt[8];
    __shared__ int lbase[8];
    int is64 = flag[0];
    int t = threadIdx.x;
    int lane = t & 63;
    int nbatch = (E + CBATCH - 1) / CBATCH;
    for (int bb = blockIdx.x; bb < nbatch; bb += gridDim.x) {
        int base = bb * CBATCH;
        if (t < 8) lcnt[t] = 0;
        __syncthreads();
        int sv[NU], dv[NU], pv[NU], lo[NU];
        bool val[NU];
        #pragma unroll
        for (int u = 0; u < NU; u++) {
            int i = base + u * 256 + t;          // coalesced within each u-step
            val[u] = i < E;
            sv[u] = 0; dv[u] = 0; lo[u] = 0;
            if (val[u]) {
                if (is64) {
                    const long long* q = (const long long*)ei;
                    sv[u] = (int)q[i]; dv[u] = (int)q[E + i];
                } else {
                    const int* q = (const int*)ei;
                    sv[u] = q[i]; dv[u] = q[E + i];
                }
                atomicAdd(&deg[dv[u]], 1);
            }
            pv[u] = val[u] ? ((dv[u] >> 12) & 7) : -1;
            // wave-aggregated reservation: 1 LDS atomic per wave per partition
            #pragma unroll
            for (int pp = 0; pp < 8; pp++) {
                unsigned long long mk = __ballot(pv[u] == pp);
                if (mk) {                         // wave-uniform branch
                    int leader = (int)__ffsll(mk) - 1;
                    int wb = 0;
                    if (lane == leader) wb = atomicAdd(&lcnt[pp], __popcll(mk));
                    wb = __shfl(wb, leader);
                    if (pv[u] == pp)
                        lo[u] = wb + (int)__popcll(mk & ((1ull << lane) - 1ull));
                }
            }
        }
        __syncthreads();
        if (t < 8) lbase[t] = atomicAdd(&pcount[t * PSTRIDE], lcnt[t]);  // 8 padded-line atomics/batch
        __syncthreads();
        #pragma unroll
        for (int u = 0; u < NU; u++) {
            if (val[u]) {
                int pos = lbase[pv[u]] + lo[u];
                if (pos < PCAP)
                    parts[(size_t)pv[u] * PCAP + pos] = make_int2(sv[u], dv[u]);
            }
        }
        __syncthreads();   // protect lcnt re-zero of next batch
    }
}

// ---- exclusive scan of deg[N] -> rowptr[N+1], 1024 elems per block ----
__global__ void scan1(const int* __restrict__ deg, int N, int* __restrict__ bsum) {
    __shared__ int lsum[256];
    int t = threadIdx.x;
    int base = blockIdx.x * 1024 + t * 4;
    int s = 0;
    #pragma unroll
    for (int i = 0; i < 4; i++) { int g = base + i; s += (g < N) ? deg[g] : 0; }
    lsum[t] = s; __syncthreads();
    for (int off = 128; off > 0; off >>= 1) {
        if (t < off) lsum[t] += lsum[t + off];
        __syncthreads();
    }
    if (t == 0) bsum[blockIdx.x] = lsum[0];
}

__global__ void scan2(int* bsum, int nb, int* rowptr, int N) {
    __shared__ int A[256], B[256];
    int t = threadIdx.x;
    if (nb <= 256) {
        int v = (t < nb) ? bsum[t] : 0;
        A[t] = v; __syncthreads();
        int* in = A; int* out = B;
        for (int off = 1; off < 256; off <<= 1) {
            out[t] = in[t] + ((t >= off) ? in[t - off] : 0);
            __syncthreads();
            int* z = in; in = out; out = z;
        }
        if (t < nb) bsum[t] = in[t] - v;            // exclusive
        if (t == 0) rowptr[N] = in[255];
    } else if (t == 0) {
        int run = 0;
        for (int i = 0; i < nb; i++) { int v = bsum[i]; bsum[i] = run; run += v; }
        rowptr[N] = run;
    }
}

__global__ void scan3(const int* __restrict__ deg, int N, const int* __restrict__ boff,
                      int* __restrict__ rowptr, float* __restrict__ dinv) {
    __shared__ int A[256], B[256];
    int t = threadIdx.x;
    int base = blockIdx.x * 1024 + t * 4;
    int v[4]; int s = 0;
    #pragma unroll
    for (int i = 0; i < 4; i++) { int g = base + i; v[i] = (g < N) ? deg[g] : 0; s += v[i]; }
    A[t] = s; __syncthreads();
    int* in = A; int* out = B;
    for (int off = 1; off < 256; off <<= 1) {
        out[t] = in[t] + ((t >= off) ? in[t - off] : 0);
        __syncthreads();
        int* tmp = in; in = out; out = tmp;
    }
    int excl = (t == 0) ? 0 : in[t - 1];
    int run = boff[blockIdx.x] + excl;
    #pragma unroll
    for (int i = 0; i < 4; i++) {
        int g = base + i;
        if (g < N) {
            rowptr[g] = run;
            dinv[g] = rsqrtf((float)(v[i] + 1));
        }
        run += v[i];
    }
}

// ---- place: group g reads ONLY its partition, scatters into its csr slice ----
__global__ __launch_bounds__(256) void place_edges(const int* __restrict__ pcount,
                                                   const int2* __restrict__ parts,
                                                   const int* __restrict__ rowptr,
                                                   int* __restrict__ cursor,
                                                   int* __restrict__ csr) {
    int g = blockIdx.x & 7;
    int cnt = pcount[g * PSTRIDE]; if (cnt > PCAP) cnt = PCAP;
    int gblk = blockIdx.x >> 3;
    int ngblk = gridDim.x >> 3;
    int j = gblk * blockDim.x + threadIdx.x;
    int gstride = ngblk * blockDim.x;
    const int2* pg = parts + (size_t)g * PCAP;
    for (; j < cnt; j += gstride) {
        int2 e = pg[j];
        int pos = rowptr[e.y] + atomicAdd(&cursor[e.y], 1);
        csr[pos] = e.x;
    }
}

// ---- y16[n,:] = half((x[n,:] @ W) * dinv[n]) — LDS-tiled 64x64 ----
template <typename TIN>
__global__ __launch_bounds__(256, 4) void gemm_scale(const TIN* __restrict__ x,
                                                     const float* __restrict__ W,
                                                     const float* __restrict__ dinv,
                                                     __half* __restrict__ y16, int N) {
    __shared__ float Xl[64 * 68];   // pad to 68 to break bank aliasing
    __shared__ float Wl[64 * 64];
    int t = threadIdx.x;
    int nbase = blockIdx.x * 64;
    for (int i = t; i < 1024; i += 256) {
        ((float4*)Wl)[i] = ((const float4*)W)[i];
    }
    for (int i = t; i < 1024; i += 256) {
        int flat = i * 4;
        int n = flat >> 6, k = flat & 63;
        int g = nbase + n;
        float4 v;
        if (g < N) {
            if constexpr (sizeof(TIN) == 2) {
                const __half2* hp = (const __half2*)((const __half*)x + (size_t)g * FDIM + k);
                float2 a = __half22float2(hp[0]);
                float2 c = __half22float2(hp[1]);
                v = make_float4(a.x, a.y, c.x, c.y);
            } else {
                v = *(const float4*)((const float*)x + (size_t)g * FDIM + k);
            }
        } else {
            v = make_float4(0.f, 0.f, 0.f, 0.f);
        }
        *(float4*)&Xl[n * 68 + k] = v;
    }
    __syncthreads();

    int fr = t & 15;    // feature group: feats fr*4..fr*4+3
    int ng = t >> 4;    // node group:    nodes ng*4..ng*4+3
    float acc[4][4] = {{0.f}};
    #pragma unroll 4
    for (int kc = 0; kc < 16; kc++) {
        float4 xa[4], wa[4];
        #pragma unroll
        for (int i = 0; i < 4; i++) xa[i] = *(float4*)&Xl[(ng * 4 + i) * 68 + kc * 4];
        #pragma unroll
        for (int j = 0; j < 4; j++) wa[j] = *(float4*)&Wl[(kc * 4 + j) * 64 + fr * 4];
        #pragma unroll
        for (int i = 0; i < 4; i++) {
            acc[i][0] += xa[i].x * wa[0].x + xa[i].y * wa[1].x + xa[i].z * wa[2].x + xa[i].w * wa[3].x;
            acc[i][1] += xa[i].x * wa[0].y + xa[i].y * wa[1].y + xa[i].z * wa[2].y + xa[i].w * wa[3].y;
            acc[i][2] += xa[i].x * wa[0].z + xa[i].y * wa[1].z + xa[i].z * wa[2].z + xa[i].w * wa[3].z;
            acc[i][3] += xa[i].x * wa[0].w + xa[i].y * wa[1].w + xa[i].z * wa[2].w + xa[i].w * wa[3].w;
        }
    }
    #pragma unroll
    for (int i = 0; i < 4; i++) {
        int g = nbase + ng * 4 + i;
        if (g < N) {
            float dv = dinv[g];
            __half2 ha = __floats2half2_rn(acc[i][0] * dv, acc[i][1] * dv);
            __half2 hb = __floats2half2_rn(acc[i][2] * dv, acc[i][3] * dv);
            union { __half2 h[2]; uint2 u; } cvt;
            cvt.h[0] = ha; cvt.h[1] = hb;
            *(uint2*)(y16 + (size_t)g * FDIM + fr * 4) = cvt.u;
        }
    }
}

__device__ __forceinline__ float4 half4_to_float4(uint2 u) {
    float2 a = __half22float2(*(__half2*)&u.x);
    float2 b = __half22float2(*(__half2*)&u.y);
    return make_float4(a.x, a.y, b.x, b.y);
}

// ---- gather: out[n,:] = dinv[n]*(y[n,:] + sum_bucket y[src,:]) + b (+ReLU) ----
// 4 edge streams x 16-lane rows: lane = 16*q + fl; each lane holds feats 4fl..4fl+3
// (uint2 = 4 halves). Streams combined via shfl_xor(16), shfl_xor(32).
template <bool RELU, typename OUT_T>
__global__ __launch_bounds__(256) void gather(const int* __restrict__ rowptr,
                                              const int* __restrict__ csr,
                                              const __half* __restrict__ y16,
                                              const float* __restrict__ dinv,
                                              const float* __restrict__ b,
                                              OUT_T* __restrict__ out, int N) {
    int lane = threadIdx.x & 63;
    int n = blockIdx.x * 4 + (threadIdx.x >> 6);
    if (n >= N) return;
    int q = lane >> 4;       // edge stream 0..3
    int fl = lane & 15;      // feature quad: feats 4fl..4fl+3
    int start = rowptr[n], end = rowptr[n + 1];
    float ax = 0.f, ay = 0.f, az = 0.f, aw = 0.f;
    for (int base = start; base < end; base += 64) {
        int m = end - base; if (m > 64) m = 64;
        int idx = (lane < m) ? csr[base + lane] : 0;
        int j = 0;
        for (; j + 7 < m; j += 8) {            // 8 edges via 2 row-loads/lane
            int s0 = __shfl(idx, j + q);
            int s1 = __shfl(idx, j + 4 + q);
            uint2 u0 = *(const uint2*)(y16 + (size_t)s0 * FDIM + 4 * fl);
            uint2 u1 = *(const uint2*)(y16 + (size_t)s1 * FDIM + 4 * fl);
            float4 f0 = half4_to_float4(u0);
            float4 f1 = half4_to_float4(u1);
            ax += f0.x + f1.x; ay += f0.y + f1.y;
            az += f0.z + f1.z; aw += f0.w + f1.w;
        }
        for (; j < m; j += 4) {                // tail: up to 4 edges, 1 load/lane
            int e = j + q;
            int se = __shfl(idx, (e < m) ? e : 0);
            uint2 u = *(const uint2*)(y16 + (size_t)se * FDIM + 4 * fl);
            if (e < m) {
                float4 f = half4_to_float4(u);
                ax += f.x; ay += f.y; az += f.z; aw += f.w;
            }
        }
    }
    // combine the 4 edge streams (lanes fl, fl+16, fl+32, fl+48)
    ax += __shfl_xor(ax, 16); ay += __shfl_xor(ay, 16);
    az += __shfl_xor(az, 16); aw += __shfl_xor(aw, 16);
    ax += __shfl_xor(ax, 32); ay += __shfl_xor(ay, 32);
    az += __shfl_xor(az, 32); aw += __shfl_xor(aw, 32);
    if (q == 0) {
        uint2 su = *(const uint2*)(y16 + (size_t)n * FDIM + 4 * fl);   // self loop
        float4 sf = half4_to_float4(su);
        float dv = dinv[n];
        float4 bb = ((const float4*)b)[fl];
        float ox = (ax + sf.x) * dv + bb.x;
        float oy = (ay + sf.y) * dv + bb.y;
        float oz = (az + sf.z) * dv + bb.z;
        float ow = (aw + sf.w) * dv + bb.w;
        if (RELU) {
            ox = fmaxf(ox, 0.f); oy = fmaxf(oy, 0.f);
            oz = fmaxf(oz, 0.f); ow = fmaxf(ow, 0.f);
        }
        if constexpr (sizeof(OUT_T) == 2) {
            union { __half2 h[2]; uint2 u; } cvt;
            cvt.h[0] = __floats2half2_rn(ox, oy);
            cvt.h[1] = __floats2half2_rn(oz, ow);
            *(uint2*)((__half*)out + (size_t)n * FDIM + 4 * fl) = cvt.u;
        } else {
            *(float4*)((float*)out + (size_t)n * FDIM + 4 * fl) = make_float4(ox, oy, oz, ow);
        }
    }
}

static inline size_t roundup256(size_t x) { return (x + 255) & ~(size_t)255; }

extern "C" void kernel_launch(void* const* d_in, const int* in_sizes, int n_in,
                              void* d_out, int out_size, void* d_ws, size_t ws_size,
                              hipStream_t stream) {
    const float* x  = (const float*)d_in[0];
    const void*  ei = d_in[1];
    const float* W1 = (const float*)d_in[2];
    const float* b1 = (const float*)d_in[3];
    const float* W2 = (const float*)d_in[4];
    const float* b2 = (const float*)d_in[5];
    float* out = (float*)d_out;

    int N = out_size / FDIM;                 // 100000
    int E = in_sizes[1] / 2;                 // 1200000
    int NB = (N + 1023) / 1024;              // scan blocks (98)
    int NBATCH = (E + CBATCH - 1) / CBATCH;  // convert batches (586)

    // ws layout (256B-aligned slots)
    char* p = (char*)d_ws;
    float* dinv  = (float*)p;  p += roundup256((size_t)N * 4);
    __half* y16  = (__half*)p; p += roundup256((size_t)N * FDIM * 2);
    __half* h16  = (__half*)p; p += roundup256((size_t)N * FDIM * 2);
    int* deg     = (int*)p;    p += roundup256((size_t)N * 4);
    int* cursor  = (int*)p;    p += roundup256((size_t)N * 4);
    int* pcount  = (int*)p;    p += 8 * PSTRIDE * 4;   // 8 padded counters (1 KiB)
    int* flag    = (int*)p;    p += 256;
    int* rowptr  = (int*)p;    p += roundup256((size_t)(N + 1) * 4);
    int* bsum    = (int*)p;    p += 1024;
    int* csr     = (int*)p;    p += roundup256((size_t)E * 4);
    int2* parts  = (int2*)p;   p += (size_t)8 * PCAP * sizeof(int2);

    // zero deg+cursor+pcount in one memset (contiguous slots)
    size_t zlen = (size_t)((char*)pcount + 8 * PSTRIDE * 4 - (char*)deg);
    hipMemsetAsync(deg, 0, zlen, stream);

    // ---- graph prep ----
    detect_dtype_kernel<<<1, 256, 0, stream>>>((const int*)ei, 2048, flag);
    convert_partition<<<NBATCH, 256, 0, stream>>>(ei, flag, E, deg, pcount, parts);
    scan1<<<NB, 256, 0, stream>>>(deg, N, bsum);
    scan2<<<1, 256, 0, stream>>>(bsum, NB, rowptr, N);
    scan3<<<NB, 256, 0, stream>>>(deg, N, bsum, rowptr, dinv);
    place_edges<<<2048, 256, 0, stream>>>(pcount, parts, rowptr, cursor, csr);

    int gemm_grid = (N + 63) / 64;
    int gath_grid = (N + 3) / 4;

    // ---- layer 1: h = relu(GCNConv(x, W1, b1)) -> h16 (fp16) ----
    gemm_scale<float><<<gemm_grid, 256, 0, stream>>>(x, W1, dinv, y16, N);
    gather<true, __half><<<gath_grid, 256, 0, stream>>>(rowptr, csr, y16, dinv, b1, h16, N);

    // ---- layer 2: out = GCNConv(h, W2, b2) -> fp32 d_out ----
    gemm_scale<__half><<<gemm_grid, 256, 0, stream>>>(h16, W2, dinv, y16, N);
    gather<false, float><<<gath_grid, 256, 0, stream>>>(rowptr, csr, y16, dinv, b2, out, N);
}